// Round 4
// baseline (637.195 us; speedup 1.0000x reference)
//
#include <hip/hip_runtime.h>
#include <hip/hip_bf16.h>
#include <hip/hip_fp16.h>
#include <math.h>

#define IN_DIM 512
#define H1     128
#define ZD     64

#define NBKT   128          // 8 a-slices x 16 b-slices
#define BCAP   18432        // per-bucket record capacity (exp 15625, +22 sigma)

typedef __attribute__((ext_vector_type(8))) short bf16x8;
typedef __attribute__((ext_vector_type(4))) float f32x4;

__device__ __forceinline__ ushort f32_to_bf16_bits(float x) {
    unsigned b = __float_as_uint(x);
    unsigned r = (b + 0x7FFF + ((b >> 16) & 1)) >> 16;  // RNE
    return (ushort)r;
}

// ---------------------------------------------------------------------------
// prepack: W (512x128 fp32) -> Whi/Wlo bf16, fragment-linear layout:
//   pack[((s*8 + cb)*64 + lane)*8 + j] = bf16 of W[s*32 + (lane>>4)*8 + j][cb*16 + (lane&15)]
// ---------------------------------------------------------------------------
__global__ void prepack_w(const float* __restrict__ W,
                          ushort* __restrict__ Whi, ushort* __restrict__ Wlo) {
    int t = blockIdx.x * 256 + threadIdx.x;       // 0..8191
    int s  = t >> 9;
    int cb = (t >> 6) & 7;
    int l  = t & 63;
    ushort h[8], lo[8];
    #pragma unroll
    for (int j = 0; j < 8; ++j) {
        int k   = s * 32 + ((l >> 4) * 8) + j;
        int col = cb * 16 + (l & 15);
        float x = W[(size_t)k * H1 + col];
        ushort hb = f32_to_bf16_bits(x);
        float  hf = __uint_as_float((unsigned)hb << 16);
        h[j]  = hb;
        lo[j] = f32_to_bf16_bits(x - hf);
    }
    size_t off = ((size_t)t) * 8;
    *(ushort4*)&Whi[off]     = make_ushort4(h[0], h[1], h[2], h[3]);
    *(ushort4*)&Whi[off + 4] = make_ushort4(h[4], h[5], h[6], h[7]);
    *(ushort4*)&Wlo[off]     = make_ushort4(lo[0], lo[1], lo[2], lo[3]);
    *(ushort4*)&Wlo[off + 4] = make_ushort4(lo[4], lo[5], lo[6], lo[7]);
}

// ---------------------------------------------------------------------------
// encode: Z = relu(X@W) @ W2   (Z stored fp16)
// GEMM1: split-bf16 MFMA, BM=64, double-buffered LDS, 1 barrier/K-step.
// LDS capped at 18.4KB (fp16 ht) -> 8 blocks/CU. Lane-linear stage writes
// (conflict-free b128). GEMM2: fp32 VALU on fp16-transposed h.
// ---------------------------------------------------------------------------
__global__ __launch_bounds__(256, 8) void encode_kernel(
    const float* __restrict__ X, const ushort* __restrict__ Whi,
    const ushort* __restrict__ Wlo, const float* __restrict__ W2,
    __half* __restrict__ Z, int N)
{
    __shared__ __align__(16) union {
        ushort st[2][2][4][512];   // [buf][hi/lo][rb][la*8+j]  16 KB
        __half ht[H1][72];         // h^T[col][row] fp16, 18.4 KB
    } sm;

    const int tid  = threadIdx.x;
    const int lane = tid & 63;
    const int w    = tid >> 6;
    const int wr   = w >> 1;
    const int wc   = w & 1;
    const int row0 = blockIdx.x * 64;

    // lane-linear staging: srb = tid>>6, la = tid&63 -> contiguous b128 writes
    const int srb  = tid >> 6;
    const int sla  = tid & 63;
    const int srow = srb * 16 + (tid & 15);
    const int kq   = (tid >> 4) & 3;
    const bool srow_ok = (row0 + srow) < N;
    const float* xp = X + (size_t)(row0 + srow) * IN_DIM + kq * 8;

    f32x4 acc[2][4];
    #pragma unroll
    for (int i = 0; i < 2; ++i)
        #pragma unroll
        for (int j = 0; j < 4; ++j) acc[i][j] = (f32x4){0.f, 0.f, 0.f, 0.f};

    float4 rgA, rgB;
    rgA = srow_ok ? *(const float4*)(xp + 0) : make_float4(0, 0, 0, 0);
    rgB = srow_ok ? *(const float4*)(xp + 4) : make_float4(0, 0, 0, 0);

    // trunc split: hi = x & 0xFFFF0000, lo = bf16(x - hi)  (exact residual)
    auto stage = [&](int buf) {
        float xv[8] = {rgA.x, rgA.y, rgA.z, rgA.w, rgB.x, rgB.y, rgB.z, rgB.w};
        unsigned hb[8], lb[8];
        #pragma unroll
        for (int j = 0; j < 8; ++j) {
            unsigned b = __float_as_uint(xv[j]);
            unsigned hf = b & 0xFFFF0000u;
            hb[j] = b;
            lb[j] = __float_as_uint(xv[j] - __uint_as_float(hf));
        }
        uint4 hp, lp;
        hp.x = (hb[0] >> 16) | (hb[1] & 0xFFFF0000u);
        hp.y = (hb[2] >> 16) | (hb[3] & 0xFFFF0000u);
        hp.z = (hb[4] >> 16) | (hb[5] & 0xFFFF0000u);
        hp.w = (hb[6] >> 16) | (hb[7] & 0xFFFF0000u);
        lp.x = (lb[0] >> 16) | (lb[1] & 0xFFFF0000u);
        lp.y = (lb[2] >> 16) | (lb[3] & 0xFFFF0000u);
        lp.z = (lb[4] >> 16) | (lb[5] & 0xFFFF0000u);
        lp.w = (lb[6] >> 16) | (lb[7] & 0xFFFF0000u);
        *(uint4*)&sm.st[buf][0][srb][sla * 8] = hp;
        *(uint4*)&sm.st[buf][1][srb][sla * 8] = lp;
    };

    stage(0);
    rgA = srow_ok ? *(const float4*)(xp + 32) : make_float4(0, 0, 0, 0);
    rgB = srow_ok ? *(const float4*)(xp + 36) : make_float4(0, 0, 0, 0);
    __syncthreads();

    for (int s = 0; s < 16; ++s) {
        const int buf = s & 1;
        bf16x8 aH[2], aL[2];
        #pragma unroll
        for (int rb = 0; rb < 2; ++rb) {
            int rbg = wr * 2 + rb;
            aH[rb] = *(const bf16x8*)&sm.st[buf][0][rbg][lane * 8];
            aL[rb] = *(const bf16x8*)&sm.st[buf][1][rbg][lane * 8];
        }
        if (s < 15) stage(buf ^ 1);
        if (s < 14) {
            const float* xp2 = xp + (s + 2) * 32;
            rgA = srow_ok ? *(const float4*)(xp2 + 0) : make_float4(0, 0, 0, 0);
            rgB = srow_ok ? *(const float4*)(xp2 + 4) : make_float4(0, 0, 0, 0);
        }
        #pragma unroll
        for (int cb = 0; cb < 4; ++cb) {
            int cbg = wc * 4 + cb;
            size_t off = ((size_t)(s * 8 + cbg) * 64 + lane) * 8;
            bf16x8 bH = *(const bf16x8*)&Whi[off];
            bf16x8 bL = *(const bf16x8*)&Wlo[off];
            #pragma unroll
            for (int rb = 0; rb < 2; ++rb) {
                acc[rb][cb] = __builtin_amdgcn_mfma_f32_16x16x32_bf16(
                    aH[rb], bH, acc[rb][cb], 0, 0, 0);
                acc[rb][cb] = __builtin_amdgcn_mfma_f32_16x16x32_bf16(
                    aH[rb], bL, acc[rb][cb], 0, 0, 0);
                acc[rb][cb] = __builtin_amdgcn_mfma_f32_16x16x32_bf16(
                    aL[rb], bH, acc[rb][cb], 0, 0, 0);
            }
        }
        __syncthreads();
    }

    // ---- write relu(h) transposed (fp16): ht[col][row_local] ----
    #pragma unroll
    for (int rb = 0; rb < 2; ++rb)
        #pragma unroll
        for (int cb = 0; cb < 4; ++cb) {
            int col = wc * 64 + cb * 16 + (lane & 15);
            int rr  = wr * 32 + rb * 16 + (lane >> 4) * 4;
            *(__half2*)&sm.ht[col][rr] =
                __floats2half2_rn(fmaxf(acc[rb][cb][0], 0.f), fmaxf(acc[rb][cb][1], 0.f));
            *(__half2*)&sm.ht[col][rr + 2] =
                __floats2half2_rn(fmaxf(acc[rb][cb][2], 0.f), fmaxf(acc[rb][cb][3], 0.f));
        }
    __syncthreads();

    // ---- GEMM2: z[r][c] = relu(h)[r][:] @ W2, K=128 ----
    const int tx = tid & 31;
    const int ty = tid >> 5;

    float zacc[8][2];
    #pragma unroll
    for (int i = 0; i < 8; ++i) { zacc[i][0] = 0.f; zacc[i][1] = 0.f; }

    #pragma unroll 4
    for (int k = 0; k < H1; ++k) {
        float2 b = *(const float2*)&W2[(size_t)k * ZD + tx * 2];
        union { uint4 u; __half2 h[4]; } hv;
        hv.u = *(const uint4*)&sm.ht[k][ty * 8];
        #pragma unroll
        for (int q = 0; q < 4; ++q) {
            float2 fa = __half22float2(hv.h[q]);
            zacc[2 * q][0]     = fmaf(fa.x, b.x, zacc[2 * q][0]);
            zacc[2 * q][1]     = fmaf(fa.x, b.y, zacc[2 * q][1]);
            zacc[2 * q + 1][0] = fmaf(fa.y, b.x, zacc[2 * q + 1][0]);
            zacc[2 * q + 1][1] = fmaf(fa.y, b.y, zacc[2 * q + 1][1]);
        }
    }
    #pragma unroll
    for (int i = 0; i < 8; ++i) {
        int gr = row0 + ty * 8 + i;
        if (gr < N)
            *(__half2*)&Z[(size_t)gr * ZD + tx * 2] =
                __floats2half2_rn(zacc[i][0], zacc[i][1]);
    }
}

// ---------------------------------------------------------------------------
// init: per-bucket write cursors = bucket base
// ---------------------------------------------------------------------------
__global__ void init_cursors(int* __restrict__ cursors) {
    int t = threadIdx.x;
    if (t < NBKT) cursors[t] = t * BCAP;
}

// ---------------------------------------------------------------------------
// scatter: bucket edges by (a-slice[8], b-slice[16]) -> recs {a,b,orig,0}.
// Per-block two-phase LDS counting; 128 global atomics per block.
// Bucketing is locality-only: any record in any bucket is still correct.
// ---------------------------------------------------------------------------
__global__ __launch_bounds__(256) void scatter_kernel(
    const int* __restrict__ e1, const int* __restrict__ e2,
    int4* __restrict__ recs, int* __restrict__ cursors, int E, float invA, float invB)
{
    __shared__ int lhist[NBKT];
    __shared__ int lcur[NBKT];
    const int tid = threadIdx.x;
    const int total = 2 * E;
    const int chunk = (total + gridDim.x - 1) / gridDim.x;
    const int start = blockIdx.x * chunk;
    const int end   = min(start + chunk, total);

    for (int i = tid; i < NBKT; i += 256) lhist[i] = 0;
    __syncthreads();

    for (int i = start + tid; i < end; i += 256) {
        int2 ab = (i < E) ? *(const int2*)&e1[2 * (size_t)i]
                          : *(const int2*)&e2[2 * (size_t)(i - E)];
        int as = min((int)(ab.x * invA), 7);
        int bs = min((int)(ab.y * invB), 15);
        atomicAdd(&lhist[as * 16 + bs], 1);
    }
    __syncthreads();
    for (int i = tid; i < NBKT; i += 256)
        lcur[i] = atomicAdd(&cursors[i], lhist[i]);
    __syncthreads();

    for (int i = start + tid; i < end; i += 256) {
        int2 ab = (i < E) ? *(const int2*)&e1[2 * (size_t)i]
                          : *(const int2*)&e2[2 * (size_t)(i - E)];
        int as = min((int)(ab.x * invA), 7);
        int bs = min((int)(ab.y * invB), 15);
        int bkt = as * 16 + bs;
        int pos = atomicAdd(&lcur[bkt], 1);
        if (pos < (bkt + 1) * BCAP)
            recs[pos] = make_int4(ab.x, ab.y, i, 0);
    }
}

// ---------------------------------------------------------------------------
// decode (bucketed): XCD k = blockIdx&7 owns a-slice k (L2-pinned, 1.6MB);
// b-slice rotates slowly (16 blocks per pair). 8 lanes/edge, fp16 rows.
// ---------------------------------------------------------------------------
__global__ __launch_bounds__(256) void decode_sorted(
    const __half* __restrict__ Zh, const int4* __restrict__ recs,
    const int* __restrict__ cursors, float* __restrict__ out)
{
    const int k = blockIdx.x & 7;
    const int m = blockIdx.x >> 3;
    const int j = m >> 4;          // b-slice 0..15
    const int t = m & 15;          // block within pair
    const int p = k * 16 + j;
    const int start = p * BCAP;
    const int end   = min(cursors[p], start + BCAP);

    const int tid  = threadIdx.x;
    const int lane = tid & 63;
    const int wv   = tid >> 6;
    const int sub  = lane >> 3;
    const int l    = lane & 7;

    for (int r = start + t * 32 + wv * 8 + sub; r < end; r += 512) {
        int4 rec = recs[r];
        union { uint4 u; __half2 h[4]; } A, B;
        A.u = *(const uint4*)&Zh[(size_t)rec.x * ZD + l * 8];
        B.u = *(const uint4*)&Zh[(size_t)rec.y * ZD + l * 8];
        float s = 0.f;
        #pragma unroll
        for (int q = 0; q < 4; ++q) {
            float2 fa = __half22float2(A.h[q]);
            float2 fb = __half22float2(B.h[q]);
            s += fa.x * fb.x + fa.y * fb.y;
        }
        s += __shfl_xor(s, 4, 64);
        s += __shfl_xor(s, 2, 64);
        s += __shfl_xor(s, 1, 64);
        if (l == 0) out[rec.z] = 1.f / (1.f + __expf(-s));
    }
}

// ---------------------------------------------------------------------------
// decode fallback (unsorted) — used if ws too small for recs
// ---------------------------------------------------------------------------
__global__ __launch_bounds__(256) void decode_kernel(
    const __half* __restrict__ Zh, const int* __restrict__ e1,
    const int* __restrict__ e2, float* __restrict__ out, int E)
{
    const int tid  = threadIdx.x;
    const int lane = tid & 63;
    const int wv   = tid >> 6;
    const int sub  = lane >> 3;
    const int l    = lane & 7;
    const int total = 2 * E;
    const int stride = gridDim.x * 32;

    for (int idx = (blockIdx.x * 4 + wv) * 8 + sub; idx < total; idx += stride) {
        const int* ep = (idx < E) ? (e1 + 2 * (size_t)idx)
                                  : (e2 + 2 * (size_t)(idx - E));
        int2 ab = *(const int2*)ep;
        union { uint4 u; __half2 h[4]; } A, B;
        A.u = *(const uint4*)&Zh[(size_t)ab.x * ZD + l * 8];
        B.u = *(const uint4*)&Zh[(size_t)ab.y * ZD + l * 8];
        float s = 0.f;
        #pragma unroll
        for (int q = 0; q < 4; ++q) {
            float2 fa = __half22float2(A.h[q]);
            float2 fb = __half22float2(B.h[q]);
            s += fa.x * fb.x + fa.y * fb.y;
        }
        s += __shfl_xor(s, 4, 64);
        s += __shfl_xor(s, 2, 64);
        s += __shfl_xor(s, 1, 64);
        if (l == 0) out[idx] = 1.f / (1.f + __expf(-s));
    }
}

extern "C" void kernel_launch(void* const* d_in, const int* in_sizes, int n_in,
                              void* d_out, int out_size, void* d_ws, size_t ws_size,
                              hipStream_t stream) {
    const float* X  = (const float*)d_in[0];
    const float* W  = (const float*)d_in[1];
    const float* W2 = (const float*)d_in[2];
    const int*   e1 = (const int*)d_in[3];
    const int*   e2 = (const int*)d_in[4];
    float* out = (float*)d_out;

    const int N = in_sizes[0] / IN_DIM;        // 100000
    const int E = in_sizes[3] / 2;             // 1000000

    // ws layout
    const size_t ZH_OFF  = 0;                          // 12.8 MB
    const size_t WHI_OFF = 12800000;                   // 128 KB
    const size_t WLO_OFF = WHI_OFF + 131072;           // 128 KB
    const size_t CUR_OFF = WLO_OFF + 131072;           // 512 B
    const size_t REC_OFF = CUR_OFF + 512;              // 37.75 MB
    const size_t NEEDED  = REC_OFF + (size_t)NBKT * BCAP * 16;

    __half* Zh  = (__half*)((char*)d_ws + ZH_OFF);
    ushort* Whi = (ushort*)((char*)d_ws + WHI_OFF);
    ushort* Wlo = (ushort*)((char*)d_ws + WLO_OFF);
    int*    cur = (int*)((char*)d_ws + CUR_OFF);
    int4*   rec = (int4*)((char*)d_ws + REC_OFF);

    prepack_w<<<32, 256, 0, stream>>>(W, Whi, Wlo);

    const int nblk = (N + 63) / 64;
    encode_kernel<<<nblk, 256, 0, stream>>>(X, Whi, Wlo, W2, Zh, N);

    if (ws_size >= NEEDED) {
        init_cursors<<<1, 128, 0, stream>>>(cur);
        float invA = 8.0f / (float)N;
        float invB = 16.0f / (float)N;
        scatter_kernel<<<256, 256, 0, stream>>>(e1, e2, rec, cur, E, invA, invB);
        decode_sorted<<<2048, 256, 0, stream>>>(Zh, rec, cur, out);
    } else {
        decode_kernel<<<2048, 256, 0, stream>>>(Zh, e1, e2, out, E);
    }
}

// Round 5
// 442.126 us; speedup vs baseline: 1.4412x; 1.4412x over previous
//
#include <hip/hip_runtime.h>
#include <hip/hip_bf16.h>
#include <hip/hip_fp16.h>
#include <math.h>

#define IN_DIM 512
#define H1     128
#define ZD     64

#define NBKT   128          // 8 a-slices x 16 b-slices
#define BCAP   18432        // per-bucket record capacity (exp 15625, +22 sigma)

typedef __attribute__((ext_vector_type(8))) short bf16x8;
typedef __attribute__((ext_vector_type(4))) float f32x4;

__device__ __forceinline__ ushort f32_to_bf16_bits(float x) {
    unsigned b = __float_as_uint(x);
    unsigned r = (b + 0x7FFF + ((b >> 16) & 1)) >> 16;  // RNE
    return (ushort)r;
}

// ---------------------------------------------------------------------------
// prepack: W (512x128 fp32) -> Whi/Wlo bf16, fragment-linear layout:
//   pack[((s*8 + cb)*64 + lane)*8 + j] = bf16 of W[s*32 + (lane>>4)*8 + j][cb*16 + (lane&15)]
// Also initializes the 128 bucket cursors (block 0).
// ---------------------------------------------------------------------------
__global__ void prepack_w(const float* __restrict__ W,
                          ushort* __restrict__ Whi, ushort* __restrict__ Wlo,
                          int* __restrict__ cursors) {
    if (blockIdx.x == 0 && threadIdx.x < NBKT)
        cursors[threadIdx.x] = threadIdx.x * BCAP;

    int t = blockIdx.x * 256 + threadIdx.x;       // 0..8191
    int s  = t >> 9;
    int cb = (t >> 6) & 7;
    int l  = t & 63;
    ushort h[8], lo[8];
    #pragma unroll
    for (int j = 0; j < 8; ++j) {
        int k   = s * 32 + ((l >> 4) * 8) + j;
        int col = cb * 16 + (l & 15);
        float x = W[(size_t)k * H1 + col];
        ushort hb = f32_to_bf16_bits(x);
        float  hf = __uint_as_float((unsigned)hb << 16);
        h[j]  = hb;
        lo[j] = f32_to_bf16_bits(x - hf);
    }
    size_t off = ((size_t)t) * 8;
    *(ushort4*)&Whi[off]     = make_ushort4(h[0], h[1], h[2], h[3]);
    *(ushort4*)&Whi[off + 4] = make_ushort4(h[4], h[5], h[6], h[7]);
    *(ushort4*)&Wlo[off]     = make_ushort4(lo[0], lo[1], lo[2], lo[3]);
    *(ushort4*)&Wlo[off + 4] = make_ushort4(lo[4], lo[5], lo[6], lo[7]);
}

// ---------------------------------------------------------------------------
// encode: Z = relu(X@W) @ W2   (Z stored fp16)
// GEMM1: split-bf16 MFMA, BM=64, double-buffered LDS, 1 barrier/K-step.
// LDS 18.4KB; lane-linear conflict-free staging. launch_bounds (256,4):
// r4 lesson — (256,8) forced VGPR<=64 -> massive scratch spill (313MB writes).
// ---------------------------------------------------------------------------
__global__ __launch_bounds__(256, 4) void encode_kernel(
    const float* __restrict__ X, const ushort* __restrict__ Whi,
    const ushort* __restrict__ Wlo, const float* __restrict__ W2,
    __half* __restrict__ Z, int N)
{
    __shared__ __align__(16) union {
        ushort st[2][2][4][512];   // [buf][hi/lo][rb][la*8+j]  16 KB
        __half ht[H1][72];         // h^T[col][row] fp16, 18.4 KB
    } sm;

    const int tid  = threadIdx.x;
    const int lane = tid & 63;
    const int w    = tid >> 6;
    const int wr   = w >> 1;
    const int wc   = w & 1;
    const int row0 = blockIdx.x * 64;

    // lane-linear staging: srb = tid>>6, la = tid&63 -> contiguous b128 writes
    const int srb  = tid >> 6;
    const int sla  = tid & 63;
    const int srow = srb * 16 + (tid & 15);
    const int kq   = (tid >> 4) & 3;
    const bool srow_ok = (row0 + srow) < N;
    const float* xp = X + (size_t)(row0 + srow) * IN_DIM + kq * 8;

    f32x4 acc[2][4];
    #pragma unroll
    for (int i = 0; i < 2; ++i)
        #pragma unroll
        for (int j = 0; j < 4; ++j) acc[i][j] = (f32x4){0.f, 0.f, 0.f, 0.f};

    float4 rgA, rgB;
    rgA = srow_ok ? *(const float4*)(xp + 0) : make_float4(0, 0, 0, 0);
    rgB = srow_ok ? *(const float4*)(xp + 4) : make_float4(0, 0, 0, 0);

    // trunc split: hi = x & 0xFFFF0000, lo = bf16(x - hi)  (exact residual)
    auto stage = [&](int buf) {
        float xv[8] = {rgA.x, rgA.y, rgA.z, rgA.w, rgB.x, rgB.y, rgB.z, rgB.w};
        unsigned hb[8], lb[8];
        #pragma unroll
        for (int j = 0; j < 8; ++j) {
            unsigned b = __float_as_uint(xv[j]);
            unsigned hf = b & 0xFFFF0000u;
            hb[j] = b;
            lb[j] = __float_as_uint(xv[j] - __uint_as_float(hf));
        }
        uint4 hp, lp;
        hp.x = (hb[0] >> 16) | (hb[1] & 0xFFFF0000u);
        hp.y = (hb[2] >> 16) | (hb[3] & 0xFFFF0000u);
        hp.z = (hb[4] >> 16) | (hb[5] & 0xFFFF0000u);
        hp.w = (hb[6] >> 16) | (hb[7] & 0xFFFF0000u);
        lp.x = (lb[0] >> 16) | (lb[1] & 0xFFFF0000u);
        lp.y = (lb[2] >> 16) | (lb[3] & 0xFFFF0000u);
        lp.z = (lb[4] >> 16) | (lb[5] & 0xFFFF0000u);
        lp.w = (lb[6] >> 16) | (lb[7] & 0xFFFF0000u);
        *(uint4*)&sm.st[buf][0][srb][sla * 8] = hp;
        *(uint4*)&sm.st[buf][1][srb][sla * 8] = lp;
    };

    stage(0);
    rgA = srow_ok ? *(const float4*)(xp + 32) : make_float4(0, 0, 0, 0);
    rgB = srow_ok ? *(const float4*)(xp + 36) : make_float4(0, 0, 0, 0);
    __syncthreads();

    for (int s = 0; s < 16; ++s) {
        const int buf = s & 1;
        bf16x8 aH[2], aL[2];
        #pragma unroll
        for (int rb = 0; rb < 2; ++rb) {
            int rbg = wr * 2 + rb;
            aH[rb] = *(const bf16x8*)&sm.st[buf][0][rbg][lane * 8];
            aL[rb] = *(const bf16x8*)&sm.st[buf][1][rbg][lane * 8];
        }
        if (s < 15) stage(buf ^ 1);
        if (s < 14) {
            const float* xp2 = xp + (s + 2) * 32;
            rgA = srow_ok ? *(const float4*)(xp2 + 0) : make_float4(0, 0, 0, 0);
            rgB = srow_ok ? *(const float4*)(xp2 + 4) : make_float4(0, 0, 0, 0);
        }
        #pragma unroll
        for (int cb = 0; cb < 4; ++cb) {
            int cbg = wc * 4 + cb;
            size_t off = ((size_t)(s * 8 + cbg) * 64 + lane) * 8;
            bf16x8 bH = *(const bf16x8*)&Whi[off];
            bf16x8 bL = *(const bf16x8*)&Wlo[off];
            #pragma unroll
            for (int rb = 0; rb < 2; ++rb) {
                acc[rb][cb] = __builtin_amdgcn_mfma_f32_16x16x32_bf16(
                    aH[rb], bH, acc[rb][cb], 0, 0, 0);
                acc[rb][cb] = __builtin_amdgcn_mfma_f32_16x16x32_bf16(
                    aH[rb], bL, acc[rb][cb], 0, 0, 0);
                acc[rb][cb] = __builtin_amdgcn_mfma_f32_16x16x32_bf16(
                    aL[rb], bH, acc[rb][cb], 0, 0, 0);
            }
        }
        __syncthreads();
    }

    // ---- write relu(h) transposed (fp16): ht[col][row_local] ----
    #pragma unroll
    for (int rb = 0; rb < 2; ++rb)
        #pragma unroll
        for (int cb = 0; cb < 4; ++cb) {
            int col = wc * 64 + cb * 16 + (lane & 15);
            int rr  = wr * 32 + rb * 16 + (lane >> 4) * 4;
            *(__half2*)&sm.ht[col][rr] =
                __floats2half2_rn(fmaxf(acc[rb][cb][0], 0.f), fmaxf(acc[rb][cb][1], 0.f));
            *(__half2*)&sm.ht[col][rr + 2] =
                __floats2half2_rn(fmaxf(acc[rb][cb][2], 0.f), fmaxf(acc[rb][cb][3], 0.f));
        }
    __syncthreads();

    // ---- GEMM2: z[r][c] = relu(h)[r][:] @ W2, K=128 ----
    const int tx = tid & 31;
    const int ty = tid >> 5;

    float zacc[8][2];
    #pragma unroll
    for (int i = 0; i < 8; ++i) { zacc[i][0] = 0.f; zacc[i][1] = 0.f; }

    #pragma unroll 4
    for (int k = 0; k < H1; ++k) {
        float2 b = *(const float2*)&W2[(size_t)k * ZD + tx * 2];
        union { uint4 u; __half2 h[4]; } hv;
        hv.u = *(const uint4*)&sm.ht[k][ty * 8];
        #pragma unroll
        for (int q = 0; q < 4; ++q) {
            float2 fa = __half22float2(hv.h[q]);
            zacc[2 * q][0]     = fmaf(fa.x, b.x, zacc[2 * q][0]);
            zacc[2 * q][1]     = fmaf(fa.x, b.y, zacc[2 * q][1]);
            zacc[2 * q + 1][0] = fmaf(fa.y, b.x, zacc[2 * q + 1][0]);
            zacc[2 * q + 1][1] = fmaf(fa.y, b.y, zacc[2 * q + 1][1]);
        }
    }
    #pragma unroll
    for (int i = 0; i < 8; ++i) {
        int gr = row0 + ty * 8 + i;
        if (gr < N)
            *(__half2*)&Z[(size_t)gr * ZD + tx * 2] =
                __floats2half2_rn(zacc[i][0], zacc[i][1]);
    }
}

// ---------------------------------------------------------------------------
// scatter: bucket edges by (a-slice[8], b-slice[16]) -> recs {a,b,orig,0}.
// Per-block two-phase LDS counting; 128 global atomics per block.
// Bucketing is locality-only: any record in any bucket is still correct.
// ---------------------------------------------------------------------------
__global__ __launch_bounds__(256) void scatter_kernel(
    const int* __restrict__ e1, const int* __restrict__ e2,
    int4* __restrict__ recs, int* __restrict__ cursors, int E, float invA, float invB)
{
    __shared__ int lhist[NBKT];
    __shared__ int lcur[NBKT];
    const int tid = threadIdx.x;
    const int total = 2 * E;
    const int chunk = (total + gridDim.x - 1) / gridDim.x;
    const int start = blockIdx.x * chunk;
    const int end   = min(start + chunk, total);

    for (int i = tid; i < NBKT; i += 256) lhist[i] = 0;
    __syncthreads();

    for (int i = start + tid; i < end; i += 256) {
        int2 ab = (i < E) ? *(const int2*)&e1[2 * (size_t)i]
                          : *(const int2*)&e2[2 * (size_t)(i - E)];
        int as = min((int)(ab.x * invA), 7);
        int bs = min((int)(ab.y * invB), 15);
        atomicAdd(&lhist[as * 16 + bs], 1);
    }
    __syncthreads();
    for (int i = tid; i < NBKT; i += 256)
        lcur[i] = atomicAdd(&cursors[i], lhist[i]);
    __syncthreads();

    for (int i = start + tid; i < end; i += 256) {
        int2 ab = (i < E) ? *(const int2*)&e1[2 * (size_t)i]
                          : *(const int2*)&e2[2 * (size_t)(i - E)];
        int as = min((int)(ab.x * invA), 7);
        int bs = min((int)(ab.y * invB), 15);
        int bkt = as * 16 + bs;
        int pos = atomicAdd(&lcur[bkt], 1);
        if (pos < (bkt + 1) * BCAP)
            recs[pos] = make_int4(ab.x, ab.y, i, 0);
    }
}

// ---------------------------------------------------------------------------
// decode (bucketed, persistent): XCD k = blockIdx&7 owns a-slice k. The
// b-slice loop is INSIDE the kernel: all 256 resident blocks of an XCD sweep
// bucket (k,0), then (k,1), ... so live L2 set = 1.6MB (a, pinned) + 0.8MB
// (current b) < 4MB. (r4 lesson: j in the grid = all b-slices live at once.)
// ---------------------------------------------------------------------------
__global__ __launch_bounds__(256) void decode_sorted(
    const __half* __restrict__ Zh, const int4* __restrict__ recs,
    const int* __restrict__ cursors, float* __restrict__ out)
{
    const int k = blockIdx.x & 7;      // XCD / a-slice
    const int t = blockIdx.x >> 3;     // 0..255 (block within XCD)
    const int tid  = threadIdx.x;
    const int lane = tid & 63;
    const int wv   = tid >> 6;
    const int sub  = lane >> 3;        // 8 edges per wave
    const int l    = lane & 7;
    const int slot = t * 32 + wv * 8 + sub;   // 0..8191

    #pragma unroll 1
    for (int j = 0; j < 16; ++j) {
        const int p = k * 16 + j;
        const int start = p * BCAP;
        const int end   = min(cursors[p], start + BCAP);
        for (int r = start + slot; r < end; r += 8192) {
            int4 rec = recs[r];
            union { uint4 u; __half2 h[4]; } A, B;
            A.u = *(const uint4*)&Zh[(size_t)rec.x * ZD + l * 8];
            B.u = *(const uint4*)&Zh[(size_t)rec.y * ZD + l * 8];
            float s = 0.f;
            #pragma unroll
            for (int q = 0; q < 4; ++q) {
                float2 fa = __half22float2(A.h[q]);
                float2 fb = __half22float2(B.h[q]);
                s += fa.x * fb.x + fa.y * fb.y;
            }
            s += __shfl_xor(s, 4, 64);
            s += __shfl_xor(s, 2, 64);
            s += __shfl_xor(s, 1, 64);
            if (l == 0) out[rec.z] = 1.f / (1.f + __expf(-s));
        }
    }
}

// ---------------------------------------------------------------------------
// decode fallback (unsorted) — used if ws too small for recs
// ---------------------------------------------------------------------------
__global__ __launch_bounds__(256) void decode_kernel(
    const __half* __restrict__ Zh, const int* __restrict__ e1,
    const int* __restrict__ e2, float* __restrict__ out, int E)
{
    const int tid  = threadIdx.x;
    const int lane = tid & 63;
    const int wv   = tid >> 6;
    const int sub  = lane >> 3;
    const int l    = lane & 7;
    const int total = 2 * E;
    const int stride = gridDim.x * 32;

    for (int idx = (blockIdx.x * 4 + wv) * 8 + sub; idx < total; idx += stride) {
        const int* ep = (idx < E) ? (e1 + 2 * (size_t)idx)
                                  : (e2 + 2 * (size_t)(idx - E));
        int2 ab = *(const int2*)ep;
        union { uint4 u; __half2 h[4]; } A, B;
        A.u = *(const uint4*)&Zh[(size_t)ab.x * ZD + l * 8];
        B.u = *(const uint4*)&Zh[(size_t)ab.y * ZD + l * 8];
        float s = 0.f;
        #pragma unroll
        for (int q = 0; q < 4; ++q) {
            float2 fa = __half22float2(A.h[q]);
            float2 fb = __half22float2(B.h[q]);
            s += fa.x * fb.x + fa.y * fb.y;
        }
        s += __shfl_xor(s, 4, 64);
        s += __shfl_xor(s, 2, 64);
        s += __shfl_xor(s, 1, 64);
        if (l == 0) out[idx] = 1.f / (1.f + __expf(-s));
    }
}

extern "C" void kernel_launch(void* const* d_in, const int* in_sizes, int n_in,
                              void* d_out, int out_size, void* d_ws, size_t ws_size,
                              hipStream_t stream) {
    const float* X  = (const float*)d_in[0];
    const float* W  = (const float*)d_in[1];
    const float* W2 = (const float*)d_in[2];
    const int*   e1 = (const int*)d_in[3];
    const int*   e2 = (const int*)d_in[4];
    float* out = (float*)d_out;

    const int N = in_sizes[0] / IN_DIM;        // 100000
    const int E = in_sizes[3] / 2;             // 1000000

    // ws layout
    const size_t ZH_OFF  = 0;                          // 12.8 MB
    const size_t WHI_OFF = 12800000;                   // 128 KB
    const size_t WLO_OFF = WHI_OFF + 131072;           // 128 KB
    const size_t CUR_OFF = WLO_OFF + 131072;           // 512 B
    const size_t REC_OFF = CUR_OFF + 512;              // 37.75 MB
    const size_t NEEDED  = REC_OFF + (size_t)NBKT * BCAP * 16;

    __half* Zh  = (__half*)((char*)d_ws + ZH_OFF);
    ushort* Whi = (ushort*)((char*)d_ws + WHI_OFF);
    ushort* Wlo = (ushort*)((char*)d_ws + WLO_OFF);
    int*    cur = (int*)((char*)d_ws + CUR_OFF);
    int4*   rec = (int4*)((char*)d_ws + REC_OFF);

    prepack_w<<<32, 256, 0, stream>>>(W, Whi, Wlo, cur);

    const int nblk = (N + 63) / 64;
    encode_kernel<<<nblk, 256, 0, stream>>>(X, Whi, Wlo, W2, Zh, N);

    if (ws_size >= NEEDED) {
        float invA = 8.0f / (float)N;
        float invB = 16.0f / (float)N;
        scatter_kernel<<<256, 256, 0, stream>>>(e1, e2, rec, cur, E, invA, invB);
        decode_sorted<<<2048, 256, 0, stream>>>(Zh, rec, cur, out);
    } else {
        decode_kernel<<<2048, 256, 0, stream>>>(Zh, e1, e2, out, E);
    }
}